// Round 2
// baseline (317.999 us; speedup 1.0000x reference)
//
#include <hip/hip_runtime.h>

#define B_DIM 2048
#define IN_DIM 1024
#define OUT_DIM 1024
#define K_KNOTS 20
#define KR (IN_DIM * K_KNOTS)   // 20480 reduction dim
#define TM 128
#define TN 128
#define BK 64
#define KSPLIT 8
#define KPB (KR / KSPLIT)       // 2560 per K-split block

typedef __bf16 bf16x8 __attribute__((ext_vector_type(8)));
typedef float  f32x4  __attribute__((ext_vector_type(4)));

__device__ __forceinline__ unsigned short f2bf(float f) {
    unsigned int u = __float_as_uint(f);
    unsigned int r = u + 0x7fffu + ((u >> 16) & 1u);   // RNE; no NaN inputs here
    return (unsigned short)(r >> 16);
}

__device__ __forceinline__ unsigned int pack2(float lo, float hi) {
    return (unsigned int)f2bf(lo) | ((unsigned int)f2bf(hi) << 16);
}

__device__ __forceinline__ void async_load16(const void* g, void* l) {
    __builtin_amdgcn_global_load_lds(
        (const __attribute__((address_space(1))) void*)g,
        (__attribute__((address_space(3))) void*)l,
        16, 0, 0);
}

// ---------------- zero the output (harness poisons it with 0xAA) -------------
__global__ void zero_out_kernel(float* out) {
    int idx = (blockIdx.x * 256 + threadIdx.x) * 4;
    float4 z = {0.f, 0.f, 0.f, 0.f};
    *(float4*)(out + idx) = z;
}

// ---------------- basis materialization: bf16 (B, IN*K) ---------------------
// one thread per bf16 PAIR (adjacent k values) -> coalesced uint stores
__global__ void basis_kernel(const float* __restrict__ x,
                             const float* __restrict__ knots,
                             unsigned int* __restrict__ out) {
    unsigned int n = blockIdx.x * 256 + threadIdx.x;    // pair index < 20,971,520
    unsigned int p  = n % 10u;                          // which k-pair
    unsigned int bi = n / 10u;                          // b*1024 + i
    float xv   = x[bi];
    float invh = 1.0f / (knots[1] - knots[0]);
    float t0 = knots[2 * p], t1 = knots[2 * p + 1];
    float d0 = (xv - t0) * invh;
    float d1 = (xv - t1) * invh;
    float v0 = __expf(-0.5f * d0 * d0);
    float v1 = __expf(-0.5f * d1 * d1);
    out[n] = pack2(v0, v1);
}

// ---------------- W fp32 -> bf16, layout preserved (OUT, IN*K) ---------------
__global__ void wconv_kernel(const float4* __restrict__ src, uint4* __restrict__ dst) {
    unsigned int t = blockIdx.x * 256 + threadIdx.x;    // handles 8 elements
    float4 a = src[2 * t];
    float4 b = src[2 * t + 1];
    uint4 o;
    o.x = pack2(a.x, a.y);
    o.y = pack2(a.z, a.w);
    o.z = pack2(b.x, b.y);
    o.w = pack2(b.z, b.w);
    dst[t] = o;
}

// ---------------- bf16 MFMA GEMM: C[b,o] += sum_r A[b,r]*W[o,r] --------------
// LDS layout (per 8-row chunk): lane l's 16B slot holds global
// (row = l>>3, colgroup = (l&7) ^ (l>>3)) -- XOR swizzle so that the
// ds_read side (16 rows x same colgroup per quad) spreads over all 8
// 4-bank groups instead of 16-way-conflicting on one.
__global__ void __launch_bounds__(256)
kan_gemm(const unsigned short* __restrict__ Ab,   // (2048, 20480) bf16 row-major
         const unsigned short* __restrict__ Bb,   // (1024, 20480) bf16 row-major
         float* __restrict__ out) {
    __shared__ __align__(16) unsigned short As[TM * BK];
    __shared__ __align__(16) unsigned short Bs[TN * BK];

    const int tid  = threadIdx.x;
    const int wave = tid >> 6;
    const int lane = tid & 63;
    const int wm = wave & 1;          // 2x2 wave grid -> each wave does 64x64
    const int wn = wave >> 1;
    const int m0 = blockIdx.x * TM;
    const int n0 = blockIdx.y * TN;
    const int k0 = blockIdx.z * KPB;

    const int srow = lane >> 3;                 // staging: row within 8-row chunk
    const int scol = ((lane & 7) ^ srow) * 8;   // staging: swizzled element col

    f32x4 acc[4][4];
#pragma unroll
    for (int i = 0; i < 4; ++i)
#pragma unroll
        for (int j = 0; j < 4; ++j) acc[i][j] = (f32x4){0.f, 0.f, 0.f, 0.f};

    for (int kt = 0; kt < KPB; kt += BK) {
        const int kb = k0 + kt;
        __syncthreads();   // previous iteration's ds_reads done before overwrite
#pragma unroll
        for (int c = 0; c < 4; ++c) {
            const int chunk = wave * 4 + c;            // 16 chunks of 8 rows
            const int r = chunk * 8 + srow;
            async_load16(Ab + (size_t)(m0 + r) * KR + kb + scol, &As[chunk * 512]);
            async_load16(Bb + (size_t)(n0 + r) * KR + kb + scol, &Bs[chunk * 512]);
        }
        __syncthreads();   // compiler drains vmcnt(0) before barrier

        const int quad = lane >> 4;
        const int r15  = lane & 15;
        const int r7   = lane & 7;
#pragma unroll
        for (int s = 0; s < 2; ++s) {
            const int cg = s * 4 + quad;               // colgroup 0..7
            const int xo = (cg ^ r7) * 8;              // unswizzled element offset
            bf16x8 af[4], bfv[4];
#pragma unroll
            for (int i = 0; i < 4; ++i) {
                af[i]  = *(const bf16x8*)&As[(wm * 64 + i * 16 + r15) * BK + xo];
                bfv[i] = *(const bf16x8*)&Bs[(wn * 64 + i * 16 + r15) * BK + xo];
            }
#pragma unroll
            for (int i = 0; i < 4; ++i)
#pragma unroll
                for (int j = 0; j < 4; ++j)
                    acc[i][j] = __builtin_amdgcn_mfma_f32_16x16x32_bf16(
                        af[i], bfv[j], acc[i][j], 0, 0, 0);
        }
    }

    // epilogue: C/D layout col=lane&15, row=(lane>>4)*4+reg
    const int quad = lane >> 4;
    const int col  = lane & 15;
#pragma unroll
    for (int i = 0; i < 4; ++i)
#pragma unroll
        for (int j = 0; j < 4; ++j)
#pragma unroll
            for (int r = 0; r < 4; ++r) {
                const int row = m0 + wm * 64 + i * 16 + quad * 4 + r;
                const int c   = n0 + wn * 64 + j * 16 + col;
                atomicAdd(&out[(size_t)row * OUT_DIM + c], acc[i][j][r]);
            }
}

// ---------------- fallback (ws too small): correctness-only fp32 -------------
__global__ void kan_fallback(const float* __restrict__ x,
                             const float* __restrict__ W,
                             const float* __restrict__ knots,
                             float* __restrict__ out) {
    __shared__ float basis[256 * K_KNOTS];   // 20 KB chunk of one b-row's basis
    const int b = blockIdx.x;
    const int o = blockIdx.y * blockDim.x + threadIdx.x;
    const float invh = 1.0f / (knots[1] - knots[0]);
    const float* w = W + (size_t)o * KR;
    float sum = 0.f;
    for (int i0 = 0; i0 < IN_DIM; i0 += 256) {
        __syncthreads();
        for (int idx = threadIdx.x; idx < 256 * K_KNOTS; idx += blockDim.x) {
            const int i = i0 + idx / K_KNOTS;
            const int k = idx % K_KNOTS;
            const float d = (x[(size_t)b * IN_DIM + i] - knots[k]) * invh;
            basis[idx] = __expf(-0.5f * d * d);
        }
        __syncthreads();
        for (int r = 0; r < 256 * K_KNOTS; ++r)
            sum += basis[r] * w[(size_t)i0 * K_KNOTS + r];
    }
    out[(size_t)b * OUT_DIM + o] = sum;
}

extern "C" void kernel_launch(void* const* d_in, const int* in_sizes, int n_in,
                              void* d_out, int out_size, void* d_ws, size_t ws_size,
                              hipStream_t stream) {
    const float* x     = (const float*)d_in[0];
    const float* W     = (const float*)d_in[1];
    const float* knots = (const float*)d_in[2];
    float* out = (float*)d_out;

    const size_t basis_bytes = (size_t)B_DIM * KR * 2;     // 80 MiB
    const size_t wb_bytes    = (size_t)OUT_DIM * KR * 2;   // 40 MiB

    if (ws_size >= basis_bytes + wb_bytes) {
        unsigned short* Ab = (unsigned short*)d_ws;
        unsigned short* Bb = (unsigned short*)((char*)d_ws + basis_bytes);

        zero_out_kernel<<<dim3((B_DIM * OUT_DIM) / (256 * 4)), dim3(256), 0, stream>>>(out);
        basis_kernel<<<dim3((B_DIM * IN_DIM * K_KNOTS / 2) / 256), dim3(256), 0, stream>>>(
            x, knots, (unsigned int*)Ab);
        wconv_kernel<<<dim3((OUT_DIM * KR / 8) / 256), dim3(256), 0, stream>>>(
            (const float4*)W, (uint4*)Bb);
        kan_gemm<<<dim3(B_DIM / TM, OUT_DIM / TN, KSPLIT), dim3(256), 0, stream>>>(Ab, Bb, out);
    } else {
        kan_fallback<<<dim3(B_DIM, OUT_DIM / 256), dim3(256), 0, stream>>>(x, W, knots, out);
    }
}

// Round 3
// 288.842 us; speedup vs baseline: 1.1009x; 1.1009x over previous
//
#include <hip/hip_runtime.h>

#define B_DIM 2048
#define IN_DIM 1024
#define OUT_DIM 1024
#define K_KNOTS 20
#define KR (IN_DIM * K_KNOTS)   // 20480 reduction dim
#define TM 128
#define TN 128
#define BK 64
#define KSPLIT 4
#define KPB (KR / KSPLIT)       // 5120 per K-split block
#define OUT_ELEMS (B_DIM * OUT_DIM)

typedef __bf16 bf16x8 __attribute__((ext_vector_type(8)));
typedef float  f32x4  __attribute__((ext_vector_type(4)));

__device__ __forceinline__ unsigned short f2bf(float f) {
    unsigned int u = __float_as_uint(f);
    unsigned int r = u + 0x7fffu + ((u >> 16) & 1u);   // RNE; no NaN inputs here
    return (unsigned short)(r >> 16);
}

__device__ __forceinline__ unsigned int pack2(float lo, float hi) {
    return (unsigned int)f2bf(lo) | ((unsigned int)f2bf(hi) << 16);
}

__device__ __forceinline__ void async_load16(const void* g, void* l) {
    __builtin_amdgcn_global_load_lds(
        (const __attribute__((address_space(1))) void*)g,
        (__attribute__((address_space(3))) void*)l,
        16, 0, 0);
}

// ---------------- zero the output (atomic fallback path only) ----------------
__global__ void zero_out_kernel(float* out) {
    int idx = (blockIdx.x * 256 + threadIdx.x) * 4;
    float4 z = {0.f, 0.f, 0.f, 0.f};
    *(float4*)(out + idx) = z;
}

// ---------------- basis materialization: bf16 (B, IN*K) ---------------------
__global__ void basis_kernel(const float* __restrict__ x,
                             const float* __restrict__ knots,
                             unsigned int* __restrict__ out) {
    unsigned int n = blockIdx.x * 256 + threadIdx.x;    // pair index < 20,971,520
    unsigned int p  = n % 10u;                          // which k-pair
    unsigned int bi = n / 10u;                          // b*1024 + i
    float xv   = x[bi];
    float invh = 1.0f / (knots[1] - knots[0]);
    float t0 = knots[2 * p], t1 = knots[2 * p + 1];
    float d0 = (xv - t0) * invh;
    float d1 = (xv - t1) * invh;
    float v0 = __expf(-0.5f * d0 * d0);
    float v1 = __expf(-0.5f * d1 * d1);
    out[n] = pack2(v0, v1);
}

// ---------------- W fp32 -> bf16, layout preserved (OUT, IN*K) ---------------
__global__ void wconv_kernel(const float4* __restrict__ src, uint4* __restrict__ dst) {
    unsigned int t = blockIdx.x * 256 + threadIdx.x;    // handles 8 elements
    float4 a = src[2 * t];
    float4 b = src[2 * t + 1];
    uint4 o;
    o.x = pack2(a.x, a.y);
    o.y = pack2(a.z, a.w);
    o.z = pack2(b.x, b.y);
    o.w = pack2(b.z, b.w);
    dst[t] = o;
}

// ---------------- bf16 MFMA GEMM: C[b,o] += sum_r A[b,r]*W[o,r] --------------
// LDS XOR swizzle keeps ds_read side conflict-free (verified: R2 conflicts=0).
// ATOMIC=false: each z-slice writes its own disjoint partial buffer (no RMW).
template <bool ATOMIC>
__global__ void __launch_bounds__(256)
kan_gemm(const unsigned short* __restrict__ Ab,   // (2048, 20480) bf16 row-major
         const unsigned short* __restrict__ Bb,   // (1024, 20480) bf16 row-major
         float* __restrict__ out) {               // out or partial base
    __shared__ __align__(16) unsigned short As[TM * BK];
    __shared__ __align__(16) unsigned short Bs[TN * BK];

    const int tid  = threadIdx.x;
    const int wave = tid >> 6;
    const int lane = tid & 63;
    const int wm = wave & 1;          // 2x2 wave grid -> each wave does 64x64
    const int wn = wave >> 1;
    const int m0 = blockIdx.x * TM;
    const int n0 = blockIdx.y * TN;
    const int k0 = blockIdx.z * KPB;

    const int srow = lane >> 3;                 // staging: row within 8-row chunk
    const int scol = ((lane & 7) ^ srow) * 8;   // staging: swizzled element col

    f32x4 acc[4][4];
#pragma unroll
    for (int i = 0; i < 4; ++i)
#pragma unroll
        for (int j = 0; j < 4; ++j) acc[i][j] = (f32x4){0.f, 0.f, 0.f, 0.f};

    for (int kt = 0; kt < KPB; kt += BK) {
        const int kb = k0 + kt;
        __syncthreads();   // previous iteration's ds_reads done before overwrite
#pragma unroll
        for (int c = 0; c < 4; ++c) {
            const int chunk = wave * 4 + c;            // 16 chunks of 8 rows
            const int r = chunk * 8 + srow;
            async_load16(Ab + (size_t)(m0 + r) * KR + kb + scol, &As[chunk * 512]);
            async_load16(Bb + (size_t)(n0 + r) * KR + kb + scol, &Bs[chunk * 512]);
        }
        __syncthreads();   // compiler drains vmcnt(0) before barrier

        const int quad = lane >> 4;
        const int r15  = lane & 15;
        const int r7   = lane & 7;
#pragma unroll
        for (int s = 0; s < 2; ++s) {
            const int cg = s * 4 + quad;               // colgroup 0..7
            const int xo = (cg ^ r7) * 8;              // unswizzled element offset
            bf16x8 af[4], bfv[4];
#pragma unroll
            for (int i = 0; i < 4; ++i) {
                af[i]  = *(const bf16x8*)&As[(wm * 64 + i * 16 + r15) * BK + xo];
                bfv[i] = *(const bf16x8*)&Bs[(wn * 64 + i * 16 + r15) * BK + xo];
            }
#pragma unroll
            for (int i = 0; i < 4; ++i)
#pragma unroll
                for (int j = 0; j < 4; ++j)
                    acc[i][j] = __builtin_amdgcn_mfma_f32_16x16x32_bf16(
                        af[i], bfv[j], acc[i][j], 0, 0, 0);
        }
    }

    // epilogue: C/D layout col=lane&15, row=(lane>>4)*4+reg
    float* dst = ATOMIC ? out : out + (size_t)blockIdx.z * OUT_ELEMS;
    const int quad = lane >> 4;
    const int col  = lane & 15;
#pragma unroll
    for (int i = 0; i < 4; ++i)
#pragma unroll
        for (int j = 0; j < 4; ++j)
#pragma unroll
            for (int r = 0; r < 4; ++r) {
                const int row = m0 + wm * 64 + i * 16 + quad * 4 + r;
                const int c   = n0 + wn * 64 + j * 16 + col;
                if (ATOMIC)
                    atomicAdd(&dst[(size_t)row * OUT_DIM + c], acc[i][j][r]);
                else
                    dst[(size_t)row * OUT_DIM + c] = acc[i][j][r];
            }
}

// ---------------- reduce KSPLIT partial slices -> out ------------------------
__global__ void kan_reduce(const float* __restrict__ part, float* __restrict__ out) {
    const int idx = (blockIdx.x * 256 + threadIdx.x) * 4;
    f32x4 s = *(const f32x4*)(part + idx);
#pragma unroll
    for (int z = 1; z < KSPLIT; ++z)
        s += *(const f32x4*)(part + (size_t)z * OUT_ELEMS + idx);
    *(f32x4*)(out + idx) = s;
}

// ---------------- fallback (ws too small): correctness-only fp32 -------------
__global__ void kan_fallback(const float* __restrict__ x,
                             const float* __restrict__ W,
                             const float* __restrict__ knots,
                             float* __restrict__ out) {
    __shared__ float basis[256 * K_KNOTS];
    const int b = blockIdx.x;
    const int o = blockIdx.y * blockDim.x + threadIdx.x;
    const float invh = 1.0f / (knots[1] - knots[0]);
    const float* w = W + (size_t)o * KR;
    float sum = 0.f;
    for (int i0 = 0; i0 < IN_DIM; i0 += 256) {
        __syncthreads();
        for (int idx = threadIdx.x; idx < 256 * K_KNOTS; idx += blockDim.x) {
            const int i = i0 + idx / K_KNOTS;
            const int k = idx % K_KNOTS;
            const float d = (x[(size_t)b * IN_DIM + i] - knots[k]) * invh;
            basis[idx] = __expf(-0.5f * d * d);
        }
        __syncthreads();
        for (int r = 0; r < 256 * K_KNOTS; ++r)
            sum += basis[r] * w[(size_t)i0 * K_KNOTS + r];
    }
    out[(size_t)b * OUT_DIM + o] = sum;
}

extern "C" void kernel_launch(void* const* d_in, const int* in_sizes, int n_in,
                              void* d_out, int out_size, void* d_ws, size_t ws_size,
                              hipStream_t stream) {
    const float* x     = (const float*)d_in[0];
    const float* W     = (const float*)d_in[1];
    const float* knots = (const float*)d_in[2];
    float* out = (float*)d_out;

    const size_t basis_bytes = (size_t)B_DIM * KR * 2;              // 80 MiB
    const size_t wb_bytes    = (size_t)OUT_DIM * KR * 2;            // 40 MiB
    const size_t part_bytes  = (size_t)KSPLIT * OUT_ELEMS * 4;      // 32 MiB

    if (ws_size >= basis_bytes + wb_bytes + part_bytes) {
        unsigned short* Ab = (unsigned short*)d_ws;
        unsigned short* Bb = (unsigned short*)((char*)d_ws + basis_bytes);
        float* part = (float*)((char*)d_ws + basis_bytes + wb_bytes);

        basis_kernel<<<dim3((B_DIM * IN_DIM * K_KNOTS / 2) / 256), dim3(256), 0, stream>>>(
            x, knots, (unsigned int*)Ab);
        wconv_kernel<<<dim3((OUT_DIM * KR / 8) / 256), dim3(256), 0, stream>>>(
            (const float4*)W, (uint4*)Bb);
        kan_gemm<false><<<dim3(B_DIM / TM, OUT_DIM / TN, KSPLIT), dim3(256), 0, stream>>>(
            Ab, Bb, part);
        kan_reduce<<<dim3(OUT_ELEMS / (256 * 4)), dim3(256), 0, stream>>>(part, out);
    } else if (ws_size >= basis_bytes + wb_bytes) {
        unsigned short* Ab = (unsigned short*)d_ws;
        unsigned short* Bb = (unsigned short*)((char*)d_ws + basis_bytes);

        zero_out_kernel<<<dim3(OUT_ELEMS / (256 * 4)), dim3(256), 0, stream>>>(out);
        basis_kernel<<<dim3((B_DIM * IN_DIM * K_KNOTS / 2) / 256), dim3(256), 0, stream>>>(
            x, knots, (unsigned int*)Ab);
        wconv_kernel<<<dim3((OUT_DIM * KR / 8) / 256), dim3(256), 0, stream>>>(
            (const float4*)W, (uint4*)Bb);
        kan_gemm<true><<<dim3(B_DIM / TM, OUT_DIM / TN, KSPLIT), dim3(256), 0, stream>>>(
            Ab, Bb, out);
    } else {
        kan_fallback<<<dim3(B_DIM, OUT_DIM / 256), dim3(256), 0, stream>>>(x, W, knots, out);
    }
}